// Round 13
// baseline (271.672 us; speedup 1.0000x reference)
//
#include <hip/hip_runtime.h>
#include <stdint.h>

// Ising PT sampler, bit-exact replay of JAX threefry2x32 (partitionable).
// R13: R12 (parity-plane SWAR, 267us) + VGPR ballast to force 1 block/CU.
// Theory: blocks are light (16.9KB LDS, 24 VGPR) so TWO 1024-thr blocks can
// co-reside per CU; with grid==CU count any packing imbalance makes some CUs
// run 2 lattices while others idle -> wall = 2x single-block time. Pinning
// ~80 dummy VGPRs (opaque asm, no memory effects) pushes VGPR_Count >64 so
// HW wave capacity (16 waves/CU at 65..128 VGPR) admits exactly one block.

#define LSZ   128
#define NB    16
#define NC    16
#define NSITES (NB*NC*LSZ*LSZ)     // 4194304
#define NBALLAST 80

// ---------------- threefry2x32 (JAX/Random123, 20 rounds) ----------------
__host__ __device__ __forceinline__ void tf2x32(uint32_t k0, uint32_t k1,
                                                uint32_t x0, uint32_t x1,
                                                uint32_t& o0, uint32_t& o1) {
  uint32_t k2 = k0 ^ k1 ^ 0x1BD11BDAu;
  x0 += k0; x1 += k1;
#define TFR(r) { x0 += x1; x1 = (x1 << (r)) | (x1 >> (32 - (r))); x1 ^= x0; }
  TFR(13) TFR(15) TFR(26) TFR(6)
  x0 += k1; x1 += k2 + 1u;
  TFR(17) TFR(29) TFR(16) TFR(24)
  x0 += k2; x1 += k0 + 2u;
  TFR(13) TFR(15) TFR(26) TFR(6)
  x0 += k0; x1 += k1 + 3u;
  TFR(17) TFR(29) TFR(16) TFR(24)
  x0 += k1; x1 += k2 + 4u;
  TFR(13) TFR(15) TFR(26) TFR(6)
  x0 += k2; x1 += k0 + 5u;
#undef TFR
  o0 = x0; o1 = x1;
}

// dual-block threefry: counters (0,xa),(0,xb), same key; bits = o0^o1.
__device__ __forceinline__ void tf2x32x2(uint32_t k0, uint32_t k1,
                                         uint32_t xa, uint32_t xb,
                                         uint32_t& oa, uint32_t& ob) {
  uint32_t k2 = k0 ^ k1 ^ 0x1BD11BDAu;
  uint32_t a0 = k0, a1 = xa + k1;
  uint32_t b0 = k0, b1 = xb + k1;
#define TFR2(r) { a0 += a1; b0 += b1; \
                  a1 = __builtin_rotateleft32(a1, r); \
                  b1 = __builtin_rotateleft32(b1, r); \
                  a1 ^= a0; b1 ^= b0; }
  TFR2(13) TFR2(15) TFR2(26) TFR2(6)
  a0 += k1; a1 += k2 + 1u; b0 += k1; b1 += k2 + 1u;
  TFR2(17) TFR2(29) TFR2(16) TFR2(24)
  a0 += k2; a1 += k0 + 2u; b0 += k2; b1 += k0 + 2u;
  TFR2(13) TFR2(15) TFR2(26) TFR2(6)
  a0 += k0; a1 += k1 + 3u; b0 += k0; b1 += k1 + 3u;
  TFR2(17) TFR2(29) TFR2(16) TFR2(24)
  a0 += k1; a1 += k2 + 4u; b0 += k1; b1 += k2 + 4u;
  TFR2(13) TFR2(15) TFR2(26) TFR2(6)
  a0 += k2; a1 += k0 + 5u; b0 += k2; b1 += k0 + 5u;
#undef TFR2
  oa = a0 ^ a1;
  ob = b0 ^ b1;
}

__device__ __forceinline__ float tf_uniform(uint32_t w) {
  union { uint32_t u; float f; } cvt;
  cvt.u = (w >> 9) | 0x3f800000u;
  return cvt.f - 1.0f;
}

// ---------------- the fused chunk kernel ----------------
// blockIdx.x = lattice id w. 1024 threads: r = t>>3 (row), h = t&7
// (8-byte group: plane bytes 8h..8h+7 == lattice columns 16h..16h+15).
// LDS layout: plane p row r -> words [p*2048 + r*16 .. +15] (64B/row/plane).
__global__ __launch_bounds__(1024) void k_chunk(const float4* __restrict__ in4,
                                                uint32_t* __restrict__ sg,
                                                const float* __restrict__ T,
                                                int* __restrict__ slotmap,
                                                const float* __restrict__ Eprev,
                                                float* __restrict__ Ecur,
                                                float* __restrict__ out,
                                                int chunk, int start, int nsw,
                                                int sample_local, int sidx,
                                                int write_E, int store_back) {
  __shared__ __align__(16) uint32_t lat32[LSZ * LSZ / 4];   // 16 KB, 2 planes
  __shared__ uint32_t kb[5][4];
  __shared__ uint32_t sh_lut[16];
  __shared__ int sh_bp;
  __shared__ int wred[16];

  const int w = blockIdx.x;
  const int t = threadIdx.x;
  const int c = w & 15;
  const int r = t >> 3;
  const int h = t & 7;

  // per-sweep keys: fold_in(base, i) then foldlike split -> (black, white)
  if (t < nsw) {
    uint32_t kk0, kk1, a, b;
    tf2x32(0u, 42u, 0u, (uint32_t)(start + t), kk0, kk1);
    tf2x32(kk0, kk1, 0u, 0u, a, b);
    kb[t][0] = a; kb[t][1] = b;
    tf2x32(kk0, kk1, 0u, 1u, a, b);
    kb[t][2] = a; kb[t][3] = b;
  }

  // lattice load into LDS (planes)
  if (chunk == 0) {
    uint32_t pw[2][2] = {{0u, 0u}, {0u, 0u}};
#pragma unroll
    for (int k = 0; k < 4; ++k) {
      float4 v = in4[(w << 12) + (r << 5) + (h << 2) + k];
      // cols 16h+4k+0..3: d0->P0 byte 2k, d1->P1 byte 2k, d2->P0 2k+1, d3->P1 2k+1
      uint32_t b0 = v.x >= 0.0f ? 1u : 0u;
      uint32_t b1 = v.y >= 0.0f ? 1u : 0u;
      uint32_t b2 = v.z >= 0.0f ? 1u : 0u;
      uint32_t b3 = v.w >= 0.0f ? 1u : 0u;
      int word = k >> 1, sh = (k & 1) * 16;
      pw[0][word] |= (b0 | (b2 << 8)) << sh;
      pw[1][word] |= (b1 | (b3 << 8)) << sh;
    }
    int base = (r << 4) + (h << 1);
    lat32[base]          = pw[0][0];
    lat32[base + 1]      = pw[0][1];
    lat32[2048 + base]     = pw[1][0];
    lat32[2048 + base + 1] = pw[1][1];
  } else {
    ((uint4*)lat32)[t] = ((const uint4*)sg)[(w << 10) + t];
  }

  // thread 0: apply previous PT event (chunks >=1), probs, LUT, publish
  if (t == 0) {
    int bp;
    if (chunk == 0) {
      bp = w >> 4;
    } else {
      bp = slotmap[w];
      int p = bp >> 1;
      float E0 = Eprev[(2 * p) * NC + c];
      float E1 = Eprev[(2 * p + 1) * NC + c];
      float b0 = 1.0f / T[2 * p];
      float b1 = 1.0f / T[2 * p + 1];
      float d = (b0 - b1) * (E0 - E1);
      uint32_t kk0, kk1, p0, p1, w0, w1;
      tf2x32(0u, 42u, 0u, (uint32_t)(start - 1), kk0, kk1);  // fold_in(base,i)
      tf2x32(kk0, kk1, 0u, 123u, p0, p1);                    // fold_in(k,123)
      tf2x32(p0, p1, 0u, (uint32_t)(p * NC + c), w0, w1);    // uniform elem
      float u = tf_uniform(w0 ^ w1);
      float pa = (d < 0.0f) ? (float)exp((double)d) : 1.0f;
      if (u < pa) bp ^= 1;
    }
    slotmap[w] = bp;
    sh_bp = bp;
    float Tb = T[bp];
    float p4 = (float)exp((double)(-4.0f / Tb));   // ref: f32 div, f32 exp
    float p8 = (float)exp((double)(-8.0f / Tb));
    // u < p  <=>  (bits>>9) < ceil(p * 2^23), exactly
    uint32_t T4 = (uint32_t)ceil((double)p4 * 8388608.0);
    uint32_t T8 = (uint32_t)ceil((double)p8 * 8388608.0);
    const uint32_t TOPEN = 0x00800000u;
    // LUT[(own<<3)|n]: own=1: n==3->T4, n==4->T8; own=0: n==1->T4, n==0->T8
    for (int i = 0; i < 16; ++i) {
      int ob = i >> 3, n = i & 7;
      uint32_t th = TOPEN;
      if (ob) { if (n == 3) th = T4; else if (n == 4) th = T8; }
      else    { if (n == 1) th = T4; else if (n == 0) th = T8; }
      sh_lut[i] = th;
    }
  }
  __syncthreads();

  // ---- VGPR ballast: pin NBALLAST registers live across the sweep loop ----
  uint32_t ballast[NBALLAST];
#pragma unroll
  for (int i = 0; i < NBALLAST; ++i) {
    ballast[i] = (uint32_t)i;
    asm volatile("" : "+v"(ballast[i]));      // opaque: not rematerializable
  }

  const int bp = sh_bp;
  const uint32_t bpc14 = ((uint32_t)((bp << 4) | c) << 14);
  const uint8_t* latb = (const uint8_t*)lat32;

  for (int sw = 0; sw < nsw; ++sw) {
    for (int par = 0; par < 2; ++par) {
      const uint32_t kk0 = kb[sw][par * 2];
      const uint32_t kk1 = kb[sw][par * 2 + 1];
      const int tp = (r + par) & 1;          // target plane (col parity)
      const int sp = tp ^ 1;

      const int ob = (tp << 11) + (r << 4) + (h << 1);  // own words
      const int ub = (tp << 11) + (((r - 1) & 127) << 4) + (h << 1);
      const int db = (tp << 11) + (((r + 1) & 127) << 4) + (h << 1);
      const int sb = (sp << 11) + (r << 4) + (h << 1);

      uint2 O = *(const uint2*)(lat32 + ob);
      uint2 U = *(const uint2*)(lat32 + ub);
      uint2 D = *(const uint2*)(lat32 + db);
      uint2 S = *(const uint2*)(lat32 + sb);
      const int ei = tp ? (((h << 3) + 8) & 63) : (((h << 3) - 1) & 63);
      uint32_t e = latb[(sp << 13) + (r << 6) + ei];

      // Sshift: tp=0 -> bytes m = S[m-1] (e at low); tp=1 -> S[m+1] (e at top)
      uint32_t s0e = (S.x << 8) | e;
      uint32_t s1e = (S.y << 8) | (S.x >> 24);
      uint32_t s0o = (S.x >> 8) | (S.y << 24);
      uint32_t s1o = (S.y >> 8) | (e << 24);
      uint32_t sh0 = tp ? s0o : s0e;
      uint32_t sh1 = tp ? s1o : s1e;

      // packed neighbor sums (bytes 0..4, no carry)
      uint32_t n0 = U.x + D.x + S.x + sh0;
      uint32_t n1 = U.y + D.y + S.y + sh1;
      // LUT index bytes: (own<<3)|n  (own byte 0/1 -> 0 or 8; n<=4)
      uint32_t i0 = (O.x << 3) | n0;
      uint32_t i1 = (O.y << 3) | n1;

      uint32_t fb = 0;
      const uint32_t cnt0 = bpc14 + ((uint32_t)r << 7) + (uint32_t)((h << 4) + tp);
#pragma unroll
      for (int m2 = 0; m2 < 4; ++m2) {
        const int ma = 2 * m2, mb2 = 2 * m2 + 1;
        uint32_t iwa = (ma < 4) ? i0 : i1;
        uint32_t iwb = (mb2 < 4) ? i0 : i1;
        uint32_t tha = sh_lut[(iwa >> (8 * (ma & 3))) & 15];
        uint32_t thb = sh_lut[(iwb >> (8 * (mb2 & 3))) & 15];
        uint32_t wa, wb;
        tf2x32x2(kk0, kk1, cnt0 + 2u * (uint32_t)ma, cnt0 + 2u * (uint32_t)mb2,
                 wa, wb);
        fb |= ((wa >> 9) < tha) ? (1u << ma) : 0u;
        fb |= ((wb >> 9) < thb) ? (1u << mb2) : 0u;
      }
      // expand accept bits -> 0x01-byte flip masks
      uint32_t xm0 = (fb & 1u) | ((fb & 2u) << 7) | ((fb & 4u) << 14)
                   | ((fb & 8u) << 21);
      uint32_t xm1 = ((fb >> 4) & 1u) | ((fb & 32u) << 3) | ((fb & 64u) << 10)
                   | ((fb & 128u) << 17);
      lat32[ob]     = O.x ^ xm0;
      lat32[ob + 1] = O.y ^ xm1;
      __syncthreads();
    }

    if (sw == sample_local) {
      // out[bp][sidx*16+c][r][16h..16h+15]: interleave planes, 0/1 -> +-1.0f
      uint2 A = *(const uint2*)(lat32 + (r << 4) + (h << 1));          // P0
      uint2 B = *(const uint2*)(lat32 + 2048 + (r << 4) + (h << 1));   // P1
      float4* dst = (float4*)out
                  + (((size_t)((bp << 5) + (sidx << 4) + c)) << 12)
                  + (r << 5) + (h << 2);
      uint32_t aw[2] = {A.x, A.y}, bw[2] = {B.x, B.y};
#pragma unroll
      for (int qd = 0; qd < 4; ++qd) {
        int lb = 2 * qd;       // local byte for elems 0/1
        float4 f;
        f.x = ((aw[lb >> 2] >> (8 * (lb & 3))) & 1u) ? 1.0f : -1.0f;
        f.y = ((bw[lb >> 2] >> (8 * (lb & 3))) & 1u) ? 1.0f : -1.0f;
        int lb1 = lb + 1;
        f.z = ((aw[lb1 >> 2] >> (8 * (lb1 & 3))) & 1u) ? 1.0f : -1.0f;
        f.w = ((bw[lb1 >> 2] >> (8 * (lb1 & 3))) & 1u) ? 1.0f : -1.0f;
        dst[qd] = f;
      }
    }
  }

  // consume ballast after the loop (keeps all NBALLAST regs live through it)
  {
    uint32_t acc = 0;
#pragma unroll
    for (int i = 0; i < NBALLAST; ++i) acc += ballast[i];
    asm volatile("" :: "v"(acc));
  }

  if (write_E) {
    // #diff over down+right bonds; E = 2*#diff - 32768 (exact int)
    uint2 A0 = *(const uint2*)(lat32 + (r << 4) + (h << 1));
    uint2 A1 = *(const uint2*)(lat32 + 2048 + (r << 4) + (h << 1));
    uint2 D0 = *(const uint2*)(lat32 + (((r + 1) & 127) << 4) + (h << 1));
    uint2 D1 = *(const uint2*)(lat32 + 2048 + (((r + 1) & 127) << 4) + (h << 1));
    uint32_t e2 = latb[(r << 6) + (((h << 3) + 8) & 63)];   // P0 row r
    uint32_t xs0 = (A0.x >> 8) | (A0.y << 24);
    uint32_t xs1 = (A0.y >> 8) | (e2 << 24);
    uint32_t tx = (A0.x ^ D0.x) + (A1.x ^ D1.x) + (A0.x ^ A1.x) + (A1.x ^ xs0);
    uint32_t ty = (A0.y ^ D0.y) + (A1.y ^ D1.y) + (A0.y ^ A1.y) + (A1.y ^ xs1);
    int psum = (int)((tx * 0x01010101u) >> 24) + (int)((ty * 0x01010101u) >> 24);
#pragma unroll
    for (int o = 32; o > 0; o >>= 1) psum += __shfl_down(psum, o, 64);
    if ((t & 63) == 0) wred[t >> 6] = psum;
    __syncthreads();
    if (t == 0) {
      int tot = 0;
#pragma unroll
      for (int i = 0; i < 16; ++i) tot += wred[i];
      Ecur[(bp << 4) | c] = (float)(2 * tot - 32768);
    }
  }

  if (store_back) {
    ((uint4*)sg)[(w << 10) + t] = ((const uint4*)lat32)[t];
  }
}

// ---------------- host ----------------
extern "C" void kernel_launch(void* const* d_in, const int* in_sizes, int n_in,
                              void* d_out, int out_size, void* d_ws, size_t ws_size,
                              hipStream_t stream) {
  const float* spins_in = (const float*)d_in[0];
  const float* T        = (const float*)d_in[1];
  uint32_t* s   = (uint32_t*)d_ws;                          // 4 MB lattice
  float*  Ea    = (float*)((char*)d_ws + (4u << 20));       // 1 KB
  float*  Eb    = (float*)((char*)d_ws + (4u << 20) + 1024);
  int*  slotmap = (int*)((char*)d_ws + (4u << 20) + 2048);  // 1 KB
  float*  out = (float*)d_out;

  // chunks split at PT events (after sweeps 0,5,10,15); samples after 14,19
  const int starts[5]  = {0, 1, 6, 11, 16};
  const int counts[5]  = {1, 5, 5, 5, 4};
  const int samploc[5] = {-1, -1, -1, 3, 3};
  const int sampidx[5] = {0, 0, 0, 0, 1};
  const int writeE[5]  = {1, 1, 1, 1, 0};
  const int storeB[5]  = {1, 1, 1, 1, 0};

  for (int ch = 0; ch < 5; ++ch) {
    float* Ecur  = (ch & 1) ? Eb : Ea;
    float* Eprev = (ch & 1) ? Ea : Eb;
    k_chunk<<<256, 1024, 0, stream>>>((const float4*)spins_in, s, T, slotmap,
                                      Eprev, Ecur, out,
                                      ch, starts[ch], counts[ch],
                                      samploc[ch], sampidx[ch],
                                      writeE[ch], storeB[ch]);
  }
}

// Round 14
// 267.427 us; speedup vs baseline: 1.0159x; 1.0159x over previous
//
#include <hip/hip_runtime.h>
#include <stdint.h>

// Ising PT sampler, bit-exact replay of JAX threefry2x32 (partitionable).
// R14: R12 kernel (best, 267us) + LDS ballast (>80KB static shared) to force
// exactly 1 block/CU — the decisive co-residency test. R13's VGPR ballast
// was clamped to 64 regs = exactly the 2-block boundary (inconclusive).
// LDS is deterministic: 82KB > 160KB/2, so the scheduler cannot pack two
// 1024-thr blocks on one CU. No instruction or semantic change vs R12.

#define LSZ   128
#define NB    16
#define NC    16
#define NSITES (NB*NC*LSZ*LSZ)     // 4194304

// ---------------- threefry2x32 (JAX/Random123, 20 rounds) ----------------
__host__ __device__ __forceinline__ void tf2x32(uint32_t k0, uint32_t k1,
                                                uint32_t x0, uint32_t x1,
                                                uint32_t& o0, uint32_t& o1) {
  uint32_t k2 = k0 ^ k1 ^ 0x1BD11BDAu;
  x0 += k0; x1 += k1;
#define TFR(r) { x0 += x1; x1 = (x1 << (r)) | (x1 >> (32 - (r))); x1 ^= x0; }
  TFR(13) TFR(15) TFR(26) TFR(6)
  x0 += k1; x1 += k2 + 1u;
  TFR(17) TFR(29) TFR(16) TFR(24)
  x0 += k2; x1 += k0 + 2u;
  TFR(13) TFR(15) TFR(26) TFR(6)
  x0 += k0; x1 += k1 + 3u;
  TFR(17) TFR(29) TFR(16) TFR(24)
  x0 += k1; x1 += k2 + 4u;
  TFR(13) TFR(15) TFR(26) TFR(6)
  x0 += k2; x1 += k0 + 5u;
#undef TFR
  o0 = x0; o1 = x1;
}

// dual-block threefry: counters (0,xa),(0,xb), same key; bits = o0^o1.
__device__ __forceinline__ void tf2x32x2(uint32_t k0, uint32_t k1,
                                         uint32_t xa, uint32_t xb,
                                         uint32_t& oa, uint32_t& ob) {
  uint32_t k2 = k0 ^ k1 ^ 0x1BD11BDAu;
  uint32_t a0 = k0, a1 = xa + k1;
  uint32_t b0 = k0, b1 = xb + k1;
#define TFR2(r) { a0 += a1; b0 += b1; \
                  a1 = __builtin_rotateleft32(a1, r); \
                  b1 = __builtin_rotateleft32(b1, r); \
                  a1 ^= a0; b1 ^= b0; }
  TFR2(13) TFR2(15) TFR2(26) TFR2(6)
  a0 += k1; a1 += k2 + 1u; b0 += k1; b1 += k2 + 1u;
  TFR2(17) TFR2(29) TFR2(16) TFR2(24)
  a0 += k2; a1 += k0 + 2u; b0 += k2; b1 += k0 + 2u;
  TFR2(13) TFR2(15) TFR2(26) TFR2(6)
  a0 += k0; a1 += k1 + 3u; b0 += k0; b1 += k1 + 3u;
  TFR2(17) TFR2(29) TFR2(16) TFR2(24)
  a0 += k1; a1 += k2 + 4u; b0 += k1; b1 += k2 + 4u;
  TFR2(13) TFR2(15) TFR2(26) TFR2(6)
  a0 += k2; a1 += k0 + 5u; b0 += k2; b1 += k0 + 5u;
#undef TFR2
  oa = a0 ^ a1;
  ob = b0 ^ b1;
}

__device__ __forceinline__ float tf_uniform(uint32_t w) {
  union { uint32_t u; float f; } cvt;
  cvt.u = (w >> 9) | 0x3f800000u;
  return cvt.f - 1.0f;
}

// ---------------- the fused chunk kernel ----------------
// blockIdx.x = lattice id w. 1024 threads: r = t>>3 (row), h = t&7
// (8-byte group: plane bytes 8h..8h+7 == lattice columns 16h..16h+15).
// LDS layout: plane p row r -> words [p*2048 + r*16 .. +15] (64B/row/plane).
__global__ __launch_bounds__(1024) void k_chunk(const float4* __restrict__ in4,
                                                uint32_t* __restrict__ sg,
                                                const float* __restrict__ T,
                                                int* __restrict__ slotmap,
                                                const float* __restrict__ Eprev,
                                                float* __restrict__ Ecur,
                                                float* __restrict__ out,
                                                int chunk, int start, int nsw,
                                                int sample_local, int sidx,
                                                int write_E, int store_back) {
  __shared__ __align__(16) uint32_t lat32[LSZ * LSZ / 4];   // 16 KB, 2 planes
  __shared__ uint32_t kb[5][4];
  __shared__ uint32_t sh_lut[16];
  __shared__ int sh_bp;
  __shared__ int wred[16];
  __shared__ uint32_t lds_ballast[16384];   // 64 KB: forces 1 block/CU

  const int w = blockIdx.x;
  const int t = threadIdx.x;
  const int c = w & 15;
  const int r = t >> 3;
  const int h = t & 7;

  // keep the ballast allocated (condition can never be true: nsw <= 5)
  if (nsw == 0x7fffffff) { lds_ballast[t] = t; Ecur[0] = (float)lds_ballast[t ^ 1]; }

  // per-sweep keys: fold_in(base, i) then foldlike split -> (black, white)
  if (t < nsw) {
    uint32_t kk0, kk1, a, b;
    tf2x32(0u, 42u, 0u, (uint32_t)(start + t), kk0, kk1);
    tf2x32(kk0, kk1, 0u, 0u, a, b);
    kb[t][0] = a; kb[t][1] = b;
    tf2x32(kk0, kk1, 0u, 1u, a, b);
    kb[t][2] = a; kb[t][3] = b;
  }

  // lattice load into LDS (planes)
  if (chunk == 0) {
    uint32_t pw[2][2] = {{0u, 0u}, {0u, 0u}};
#pragma unroll
    for (int k = 0; k < 4; ++k) {
      float4 v = in4[(w << 12) + (r << 5) + (h << 2) + k];
      // cols 16h+4k+0..3: d0->P0 byte 2k, d1->P1 byte 2k, d2->P0 2k+1, d3->P1 2k+1
      uint32_t b0 = v.x >= 0.0f ? 1u : 0u;
      uint32_t b1 = v.y >= 0.0f ? 1u : 0u;
      uint32_t b2 = v.z >= 0.0f ? 1u : 0u;
      uint32_t b3 = v.w >= 0.0f ? 1u : 0u;
      int word = k >> 1, sh = (k & 1) * 16;
      pw[0][word] |= (b0 | (b2 << 8)) << sh;
      pw[1][word] |= (b1 | (b3 << 8)) << sh;
    }
    int base = (r << 4) + (h << 1);
    lat32[base]          = pw[0][0];
    lat32[base + 1]      = pw[0][1];
    lat32[2048 + base]     = pw[1][0];
    lat32[2048 + base + 1] = pw[1][1];
  } else {
    ((uint4*)lat32)[t] = ((const uint4*)sg)[(w << 10) + t];
  }

  // thread 0: apply previous PT event (chunks >=1), probs, LUT, publish
  if (t == 0) {
    int bp;
    if (chunk == 0) {
      bp = w >> 4;
    } else {
      bp = slotmap[w];
      int p = bp >> 1;
      float E0 = Eprev[(2 * p) * NC + c];
      float E1 = Eprev[(2 * p + 1) * NC + c];
      float b0 = 1.0f / T[2 * p];
      float b1 = 1.0f / T[2 * p + 1];
      float d = (b0 - b1) * (E0 - E1);
      uint32_t kk0, kk1, p0, p1, w0, w1;
      tf2x32(0u, 42u, 0u, (uint32_t)(start - 1), kk0, kk1);  // fold_in(base,i)
      tf2x32(kk0, kk1, 0u, 123u, p0, p1);                    // fold_in(k,123)
      tf2x32(p0, p1, 0u, (uint32_t)(p * NC + c), w0, w1);    // uniform elem
      float u = tf_uniform(w0 ^ w1);
      float pa = (d < 0.0f) ? (float)exp((double)d) : 1.0f;
      if (u < pa) bp ^= 1;
    }
    slotmap[w] = bp;
    sh_bp = bp;
    float Tb = T[bp];
    float p4 = (float)exp((double)(-4.0f / Tb));   // ref: f32 div, f32 exp
    float p8 = (float)exp((double)(-8.0f / Tb));
    // u < p  <=>  (bits>>9) < ceil(p * 2^23), exactly
    uint32_t T4 = (uint32_t)ceil((double)p4 * 8388608.0);
    uint32_t T8 = (uint32_t)ceil((double)p8 * 8388608.0);
    const uint32_t TOPEN = 0x00800000u;
    // LUT[(own<<3)|n]: own=1: n==3->T4, n==4->T8; own=0: n==1->T4, n==0->T8
    for (int i = 0; i < 16; ++i) {
      int ob = i >> 3, n = i & 7;
      uint32_t th = TOPEN;
      if (ob) { if (n == 3) th = T4; else if (n == 4) th = T8; }
      else    { if (n == 1) th = T4; else if (n == 0) th = T8; }
      sh_lut[i] = th;
    }
  }
  __syncthreads();

  const int bp = sh_bp;
  const uint32_t bpc14 = ((uint32_t)((bp << 4) | c) << 14);
  const uint8_t* latb = (const uint8_t*)lat32;

  for (int sw = 0; sw < nsw; ++sw) {
    for (int par = 0; par < 2; ++par) {
      const uint32_t kk0 = kb[sw][par * 2];
      const uint32_t kk1 = kb[sw][par * 2 + 1];
      const int tp = (r + par) & 1;          // target plane (col parity)
      const int sp = tp ^ 1;

      const int ob = (tp << 11) + (r << 4) + (h << 1);  // own words
      const int ub = (tp << 11) + (((r - 1) & 127) << 4) + (h << 1);
      const int db = (tp << 11) + (((r + 1) & 127) << 4) + (h << 1);
      const int sb = (sp << 11) + (r << 4) + (h << 1);

      uint2 O = *(const uint2*)(lat32 + ob);
      uint2 U = *(const uint2*)(lat32 + ub);
      uint2 D = *(const uint2*)(lat32 + db);
      uint2 S = *(const uint2*)(lat32 + sb);
      const int ei = tp ? (((h << 3) + 8) & 63) : (((h << 3) - 1) & 63);
      uint32_t e = latb[(sp << 13) + (r << 6) + ei];

      // Sshift: tp=0 -> bytes m = S[m-1] (e at low); tp=1 -> S[m+1] (e at top)
      uint32_t s0e = (S.x << 8) | e;
      uint32_t s1e = (S.y << 8) | (S.x >> 24);
      uint32_t s0o = (S.x >> 8) | (S.y << 24);
      uint32_t s1o = (S.y >> 8) | (e << 24);
      uint32_t sh0 = tp ? s0o : s0e;
      uint32_t sh1 = tp ? s1o : s1e;

      // packed neighbor sums (bytes 0..4, no carry)
      uint32_t n0 = U.x + D.x + S.x + sh0;
      uint32_t n1 = U.y + D.y + S.y + sh1;
      // LUT index bytes: (own<<3)|n  (own byte 0/1 -> 0 or 8; n<=4)
      uint32_t i0 = (O.x << 3) | n0;
      uint32_t i1 = (O.y << 3) | n1;

      uint32_t fb = 0;
      const uint32_t cnt0 = bpc14 + ((uint32_t)r << 7) + (uint32_t)((h << 4) + tp);
#pragma unroll
      for (int m2 = 0; m2 < 4; ++m2) {
        const int ma = 2 * m2, mb2 = 2 * m2 + 1;
        uint32_t iwa = (ma < 4) ? i0 : i1;
        uint32_t iwb = (mb2 < 4) ? i0 : i1;
        uint32_t tha = sh_lut[(iwa >> (8 * (ma & 3))) & 15];
        uint32_t thb = sh_lut[(iwb >> (8 * (mb2 & 3))) & 15];
        uint32_t wa, wb;
        tf2x32x2(kk0, kk1, cnt0 + 2u * (uint32_t)ma, cnt0 + 2u * (uint32_t)mb2,
                 wa, wb);
        fb |= ((wa >> 9) < tha) ? (1u << ma) : 0u;
        fb |= ((wb >> 9) < thb) ? (1u << mb2) : 0u;
      }
      // expand accept bits -> 0x01-byte flip masks
      uint32_t xm0 = (fb & 1u) | ((fb & 2u) << 7) | ((fb & 4u) << 14)
                   | ((fb & 8u) << 21);
      uint32_t xm1 = ((fb >> 4) & 1u) | ((fb & 32u) << 3) | ((fb & 64u) << 10)
                   | ((fb & 128u) << 17);
      lat32[ob]     = O.x ^ xm0;
      lat32[ob + 1] = O.y ^ xm1;
      __syncthreads();
    }

    if (sw == sample_local) {
      // out[bp][sidx*16+c][r][16h..16h+15]: interleave planes, 0/1 -> +-1.0f
      uint2 A = *(const uint2*)(lat32 + (r << 4) + (h << 1));          // P0
      uint2 B = *(const uint2*)(lat32 + 2048 + (r << 4) + (h << 1));   // P1
      float4* dst = (float4*)out
                  + (((size_t)((bp << 5) + (sidx << 4) + c)) << 12)
                  + (r << 5) + (h << 2);
      uint32_t aw[2] = {A.x, A.y}, bw[2] = {B.x, B.y};
#pragma unroll
      for (int qd = 0; qd < 4; ++qd) {
        int lb = 2 * qd;       // local byte for elems 0/1
        float4 f;
        f.x = ((aw[lb >> 2] >> (8 * (lb & 3))) & 1u) ? 1.0f : -1.0f;
        f.y = ((bw[lb >> 2] >> (8 * (lb & 3))) & 1u) ? 1.0f : -1.0f;
        int lb1 = lb + 1;
        f.z = ((aw[lb1 >> 2] >> (8 * (lb1 & 3))) & 1u) ? 1.0f : -1.0f;
        f.w = ((bw[lb1 >> 2] >> (8 * (lb1 & 3))) & 1u) ? 1.0f : -1.0f;
        dst[qd] = f;
      }
    }
  }

  if (write_E) {
    // #diff over down+right bonds; E = 2*#diff - 32768 (exact int)
    uint2 A0 = *(const uint2*)(lat32 + (r << 4) + (h << 1));
    uint2 A1 = *(const uint2*)(lat32 + 2048 + (r << 4) + (h << 1));
    uint2 D0 = *(const uint2*)(lat32 + (((r + 1) & 127) << 4) + (h << 1));
    uint2 D1 = *(const uint2*)(lat32 + 2048 + (((r + 1) & 127) << 4) + (h << 1));
    uint32_t e2 = latb[(r << 6) + (((h << 3) + 8) & 63)];   // P0 row r
    uint32_t xs0 = (A0.x >> 8) | (A0.y << 24);
    uint32_t xs1 = (A0.y >> 8) | (e2 << 24);
    uint32_t tx = (A0.x ^ D0.x) + (A1.x ^ D1.x) + (A0.x ^ A1.x) + (A1.x ^ xs0);
    uint32_t ty = (A0.y ^ D0.y) + (A1.y ^ D1.y) + (A0.y ^ A1.y) + (A1.y ^ xs1);
    int psum = (int)((tx * 0x01010101u) >> 24) + (int)((ty * 0x01010101u) >> 24);
#pragma unroll
    for (int o = 32; o > 0; o >>= 1) psum += __shfl_down(psum, o, 64);
    if ((t & 63) == 0) wred[t >> 6] = psum;
    __syncthreads();
    if (t == 0) {
      int tot = 0;
#pragma unroll
      for (int i = 0; i < 16; ++i) tot += wred[i];
      Ecur[(bp << 4) | c] = (float)(2 * tot - 32768);
    }
  }

  if (store_back) {
    ((uint4*)sg)[(w << 10) + t] = ((const uint4*)lat32)[t];
  }
}

// ---------------- host ----------------
extern "C" void kernel_launch(void* const* d_in, const int* in_sizes, int n_in,
                              void* d_out, int out_size, void* d_ws, size_t ws_size,
                              hipStream_t stream) {
  const float* spins_in = (const float*)d_in[0];
  const float* T        = (const float*)d_in[1];
  uint32_t* s   = (uint32_t*)d_ws;                          // 4 MB lattice
  float*  Ea    = (float*)((char*)d_ws + (4u << 20));       // 1 KB
  float*  Eb    = (float*)((char*)d_ws + (4u << 20) + 1024);
  int*  slotmap = (int*)((char*)d_ws + (4u << 20) + 2048);  // 1 KB
  float*  out = (float*)d_out;

  // chunks split at PT events (after sweeps 0,5,10,15); samples after 14,19
  const int starts[5]  = {0, 1, 6, 11, 16};
  const int counts[5]  = {1, 5, 5, 5, 4};
  const int samploc[5] = {-1, -1, -1, 3, 3};
  const int sampidx[5] = {0, 0, 0, 0, 1};
  const int writeE[5]  = {1, 1, 1, 1, 0};
  const int storeB[5]  = {1, 1, 1, 1, 0};

  for (int ch = 0; ch < 5; ++ch) {
    float* Ecur  = (ch & 1) ? Eb : Ea;
    float* Eprev = (ch & 1) ? Ea : Eb;
    k_chunk<<<256, 1024, 0, stream>>>((const float4*)spins_in, s, T, slotmap,
                                      Eprev, Ecur, out,
                                      ch, starts[ch], counts[ch],
                                      samploc[ch], sampidx[ch],
                                      writeE[ch], storeB[ch]);
  }
}

// Round 15
// 267.334 us; speedup vs baseline: 1.0162x; 1.0003x over previous
//
#include <hip/hip_runtime.h>
#include <stdint.h>

// Ising PT sampler, bit-exact replay of JAX threefry2x32 (partitionable).
// R15: R12 (best, 267us; ballasts reverted) + RNG software-pipelining:
// the white half-sweep's threefry words are lattice-independent, so they
// are computed during the black interval (before the barrier) and held in
// registers; the white interval is then just gather+LUT+compare+write.
// Counters/keys unchanged -> bitstream identical.

#define LSZ   128
#define NB    16
#define NC    16
#define NSITES (NB*NC*LSZ*LSZ)     // 4194304

// ---------------- threefry2x32 (JAX/Random123, 20 rounds) ----------------
__host__ __device__ __forceinline__ void tf2x32(uint32_t k0, uint32_t k1,
                                                uint32_t x0, uint32_t x1,
                                                uint32_t& o0, uint32_t& o1) {
  uint32_t k2 = k0 ^ k1 ^ 0x1BD11BDAu;
  x0 += k0; x1 += k1;
#define TFR(r) { x0 += x1; x1 = (x1 << (r)) | (x1 >> (32 - (r))); x1 ^= x0; }
  TFR(13) TFR(15) TFR(26) TFR(6)
  x0 += k1; x1 += k2 + 1u;
  TFR(17) TFR(29) TFR(16) TFR(24)
  x0 += k2; x1 += k0 + 2u;
  TFR(13) TFR(15) TFR(26) TFR(6)
  x0 += k0; x1 += k1 + 3u;
  TFR(17) TFR(29) TFR(16) TFR(24)
  x0 += k1; x1 += k2 + 4u;
  TFR(13) TFR(15) TFR(26) TFR(6)
  x0 += k2; x1 += k0 + 5u;
#undef TFR
  o0 = x0; o1 = x1;
}

// dual-block threefry: counters (0,xa),(0,xb), same key; bits = o0^o1.
__device__ __forceinline__ void tf2x32x2(uint32_t k0, uint32_t k1,
                                         uint32_t xa, uint32_t xb,
                                         uint32_t& oa, uint32_t& ob) {
  uint32_t k2 = k0 ^ k1 ^ 0x1BD11BDAu;
  uint32_t a0 = k0, a1 = xa + k1;
  uint32_t b0 = k0, b1 = xb + k1;
#define TFR2(r) { a0 += a1; b0 += b1; \
                  a1 = __builtin_rotateleft32(a1, r); \
                  b1 = __builtin_rotateleft32(b1, r); \
                  a1 ^= a0; b1 ^= b0; }
  TFR2(13) TFR2(15) TFR2(26) TFR2(6)
  a0 += k1; a1 += k2 + 1u; b0 += k1; b1 += k2 + 1u;
  TFR2(17) TFR2(29) TFR2(16) TFR2(24)
  a0 += k2; a1 += k0 + 2u; b0 += k2; b1 += k0 + 2u;
  TFR2(13) TFR2(15) TFR2(26) TFR2(6)
  a0 += k0; a1 += k1 + 3u; b0 += k0; b1 += k1 + 3u;
  TFR2(17) TFR2(29) TFR2(16) TFR2(24)
  a0 += k1; a1 += k2 + 4u; b0 += k1; b1 += k2 + 4u;
  TFR2(13) TFR2(15) TFR2(26) TFR2(6)
  a0 += k2; a1 += k0 + 5u; b0 += k2; b1 += k0 + 5u;
#undef TFR2
  oa = a0 ^ a1;
  ob = b0 ^ b1;
}

__device__ __forceinline__ float tf_uniform(uint32_t w) {
  union { uint32_t u; float f; } cvt;
  cvt.u = (w >> 9) | 0x3f800000u;
  return cvt.f - 1.0f;
}

// gather own/neighbor plane words, build LUT-index bytes (own<<3)|n
__device__ __forceinline__ void gather_idx(const uint32_t* lat32, int r, int h,
                                           int tp, uint2& O, int& ob_out,
                                           uint32_t& i0, uint32_t& i1) {
  const int sp = tp ^ 1;
  const int ob = (tp << 11) + (r << 4) + (h << 1);
  const int ub = (tp << 11) + (((r - 1) & 127) << 4) + (h << 1);
  const int db = (tp << 11) + (((r + 1) & 127) << 4) + (h << 1);
  const int sb = (sp << 11) + (r << 4) + (h << 1);
  O = *(const uint2*)(lat32 + ob);
  uint2 U = *(const uint2*)(lat32 + ub);
  uint2 D = *(const uint2*)(lat32 + db);
  uint2 S = *(const uint2*)(lat32 + sb);
  const uint8_t* latb = (const uint8_t*)lat32;
  const int ei = tp ? (((h << 3) + 8) & 63) : (((h << 3) - 1) & 63);
  uint32_t e = latb[(sp << 13) + (r << 6) + ei];
  // Sshift: tp=0 -> bytes m = S[m-1] (e at low); tp=1 -> S[m+1] (e at top)
  uint32_t s0e = (S.x << 8) | e;
  uint32_t s1e = (S.y << 8) | (S.x >> 24);
  uint32_t s0o = (S.x >> 8) | (S.y << 24);
  uint32_t s1o = (S.y >> 8) | (e << 24);
  uint32_t sh0 = tp ? s0o : s0e;
  uint32_t sh1 = tp ? s1o : s1e;
  uint32_t n0 = U.x + D.x + S.x + sh0;      // packed byte sums, no carry
  uint32_t n1 = U.y + D.y + S.y + sh1;
  i0 = (O.x << 3) | n0;
  i1 = (O.y << 3) | n1;
  ob_out = ob;
}

// expand accept bits -> 0x01-byte flip masks, XOR into own words
__device__ __forceinline__ void apply_flip(uint32_t* lat32, int ob, uint2 O,
                                           uint32_t fb) {
  uint32_t xm0 = (fb & 1u) | ((fb & 2u) << 7) | ((fb & 4u) << 14)
               | ((fb & 8u) << 21);
  uint32_t xm1 = ((fb >> 4) & 1u) | ((fb & 32u) << 3) | ((fb & 64u) << 10)
               | ((fb & 128u) << 17);
  lat32[ob]     = O.x ^ xm0;
  lat32[ob + 1] = O.y ^ xm1;
}

// ---------------- the fused chunk kernel ----------------
// blockIdx.x = lattice id w. 1024 threads: r = t>>3 (row), h = t&7
// (8-byte group: plane bytes 8h..8h+7 == lattice columns 16h..16h+15).
// LDS layout: plane p row r -> words [p*2048 + r*16 .. +15] (64B/row/plane).
__global__ __launch_bounds__(1024) void k_chunk(const float4* __restrict__ in4,
                                                uint32_t* __restrict__ sg,
                                                const float* __restrict__ T,
                                                int* __restrict__ slotmap,
                                                const float* __restrict__ Eprev,
                                                float* __restrict__ Ecur,
                                                float* __restrict__ out,
                                                int chunk, int start, int nsw,
                                                int sample_local, int sidx,
                                                int write_E, int store_back) {
  __shared__ __align__(16) uint32_t lat32[LSZ * LSZ / 4];   // 16 KB, 2 planes
  __shared__ uint32_t kb[5][4];
  __shared__ uint32_t sh_lut[16];
  __shared__ int sh_bp;
  __shared__ int wred[16];

  const int w = blockIdx.x;
  const int t = threadIdx.x;
  const int c = w & 15;
  const int r = t >> 3;
  const int h = t & 7;

  // per-sweep keys: fold_in(base, i) then foldlike split -> (black, white)
  if (t < nsw) {
    uint32_t kk0, kk1, a, b;
    tf2x32(0u, 42u, 0u, (uint32_t)(start + t), kk0, kk1);
    tf2x32(kk0, kk1, 0u, 0u, a, b);
    kb[t][0] = a; kb[t][1] = b;
    tf2x32(kk0, kk1, 0u, 1u, a, b);
    kb[t][2] = a; kb[t][3] = b;
  }

  // lattice load into LDS (planes)
  if (chunk == 0) {
    uint32_t pw[2][2] = {{0u, 0u}, {0u, 0u}};
#pragma unroll
    for (int k = 0; k < 4; ++k) {
      float4 v = in4[(w << 12) + (r << 5) + (h << 2) + k];
      // cols 16h+4k+0..3: d0->P0 byte 2k, d1->P1 byte 2k, d2->P0 2k+1, d3->P1 2k+1
      uint32_t b0 = v.x >= 0.0f ? 1u : 0u;
      uint32_t b1 = v.y >= 0.0f ? 1u : 0u;
      uint32_t b2 = v.z >= 0.0f ? 1u : 0u;
      uint32_t b3 = v.w >= 0.0f ? 1u : 0u;
      int word = k >> 1, sh = (k & 1) * 16;
      pw[0][word] |= (b0 | (b2 << 8)) << sh;
      pw[1][word] |= (b1 | (b3 << 8)) << sh;
    }
    int base = (r << 4) + (h << 1);
    lat32[base]            = pw[0][0];
    lat32[base + 1]        = pw[0][1];
    lat32[2048 + base]     = pw[1][0];
    lat32[2048 + base + 1] = pw[1][1];
  } else {
    ((uint4*)lat32)[t] = ((const uint4*)sg)[(w << 10) + t];
  }

  // thread 0: apply previous PT event (chunks >=1), probs, LUT, publish
  if (t == 0) {
    int bp;
    if (chunk == 0) {
      bp = w >> 4;
    } else {
      bp = slotmap[w];
      int p = bp >> 1;
      float E0 = Eprev[(2 * p) * NC + c];
      float E1 = Eprev[(2 * p + 1) * NC + c];
      float b0 = 1.0f / T[2 * p];
      float b1 = 1.0f / T[2 * p + 1];
      float d = (b0 - b1) * (E0 - E1);
      uint32_t kk0, kk1, p0, p1, w0, w1;
      tf2x32(0u, 42u, 0u, (uint32_t)(start - 1), kk0, kk1);  // fold_in(base,i)
      tf2x32(kk0, kk1, 0u, 123u, p0, p1);                    // fold_in(k,123)
      tf2x32(p0, p1, 0u, (uint32_t)(p * NC + c), w0, w1);    // uniform elem
      float u = tf_uniform(w0 ^ w1);
      float pa = (d < 0.0f) ? (float)exp((double)d) : 1.0f;
      if (u < pa) bp ^= 1;
    }
    slotmap[w] = bp;
    sh_bp = bp;
    float Tb = T[bp];
    float p4 = (float)exp((double)(-4.0f / Tb));   // ref: f32 div, f32 exp
    float p8 = (float)exp((double)(-8.0f / Tb));
    // u < p  <=>  (bits>>9) < ceil(p * 2^23), exactly
    uint32_t T4 = (uint32_t)ceil((double)p4 * 8388608.0);
    uint32_t T8 = (uint32_t)ceil((double)p8 * 8388608.0);
    const uint32_t TOPEN = 0x00800000u;
    // LUT[(own<<3)|n]: own=1: n==3->T4, n==4->T8; own=0: n==1->T4, n==0->T8
    for (int i = 0; i < 16; ++i) {
      int ob = i >> 3, n = i & 7;
      uint32_t th = TOPEN;
      if (ob) { if (n == 3) th = T4; else if (n == 4) th = T8; }
      else    { if (n == 1) th = T4; else if (n == 0) th = T8; }
      sh_lut[i] = th;
    }
  }
  __syncthreads();

  const int bp = sh_bp;
  const uint32_t bpc14 = ((uint32_t)((bp << 4) | c) << 14);
  const int tpb = r & 1;          // black target plane for this row
  const int tpw = tpb ^ 1;        // white target plane
  const uint32_t cb0 = bpc14 + ((uint32_t)r << 7) + (uint32_t)((h << 4) + tpb);
  const uint32_t cw0 = bpc14 + ((uint32_t)r << 7) + (uint32_t)((h << 4) + tpw);

  for (int sw = 0; sw < nsw; ++sw) {
    const uint32_t bk0 = kb[sw][0], bk1 = kb[sw][1];
    const uint32_t wk0 = kb[sw][2], wk1 = kb[sw][3];

    // ---- interval A: black full update + white threefry (hoisted) ----
    {
      uint2 O; int ob; uint32_t i0, i1;
      gather_idx(lat32, r, h, tpb, O, ob, i0, i1);
      uint32_t fb = 0;
#pragma unroll
      for (int m2 = 0; m2 < 4; ++m2) {
        const int ma = 2 * m2, mb2 = 2 * m2 + 1;
        uint32_t iwa = (ma < 4) ? i0 : i1;
        uint32_t iwb = (mb2 < 4) ? i0 : i1;
        uint32_t tha = sh_lut[(iwa >> (8 * (ma & 3))) & 15];
        uint32_t thb = sh_lut[(iwb >> (8 * (mb2 & 3))) & 15];
        uint32_t wa, wb;
        tf2x32x2(bk0, bk1, cb0 + 4u * (uint32_t)m2, cb0 + 4u * (uint32_t)m2 + 2u,
                 wa, wb);
        fb |= ((wa >> 9) < tha) ? (1u << ma) : 0u;
        fb |= ((wb >> 9) < thb) ? (1u << mb2) : 0u;
      }
      apply_flip(lat32, ob, O, fb);
    }
    // white threefry words (lattice-independent), held in registers
    uint32_t ww[8];
#pragma unroll
    for (int m2 = 0; m2 < 4; ++m2)
      tf2x32x2(wk0, wk1, cw0 + 4u * (uint32_t)m2, cw0 + 4u * (uint32_t)m2 + 2u,
               ww[2 * m2], ww[2 * m2 + 1]);
    __syncthreads();

    // ---- interval B: white gather + apply with stored words ----
    {
      uint2 O; int ob; uint32_t i0, i1;
      gather_idx(lat32, r, h, tpw, O, ob, i0, i1);
      uint32_t fw = 0;
#pragma unroll
      for (int m = 0; m < 8; ++m) {
        uint32_t iw = (m < 4) ? i0 : i1;
        uint32_t th = sh_lut[(iw >> (8 * (m & 3))) & 15];
        fw |= ((ww[m] >> 9) < th) ? (1u << m) : 0u;
      }
      apply_flip(lat32, ob, O, fw);
    }
    __syncthreads();

    if (sw == sample_local) {
      // out[bp][sidx*16+c][r][16h..16h+15]: interleave planes, 0/1 -> +-1.0f
      uint2 A = *(const uint2*)(lat32 + (r << 4) + (h << 1));          // P0
      uint2 B = *(const uint2*)(lat32 + 2048 + (r << 4) + (h << 1));   // P1
      float4* dst = (float4*)out
                  + (((size_t)((bp << 5) + (sidx << 4) + c)) << 12)
                  + (r << 5) + (h << 2);
      uint32_t aw[2] = {A.x, A.y}, bw[2] = {B.x, B.y};
#pragma unroll
      for (int qd = 0; qd < 4; ++qd) {
        int lb = 2 * qd;       // local byte for elems 0/1
        float4 f;
        f.x = ((aw[lb >> 2] >> (8 * (lb & 3))) & 1u) ? 1.0f : -1.0f;
        f.y = ((bw[lb >> 2] >> (8 * (lb & 3))) & 1u) ? 1.0f : -1.0f;
        int lb1 = lb + 1;
        f.z = ((aw[lb1 >> 2] >> (8 * (lb1 & 3))) & 1u) ? 1.0f : -1.0f;
        f.w = ((bw[lb1 >> 2] >> (8 * (lb1 & 3))) & 1u) ? 1.0f : -1.0f;
        dst[qd] = f;
      }
    }
  }

  if (write_E) {
    // #diff over down+right bonds; E = 2*#diff - 32768 (exact int)
    const uint8_t* latb = (const uint8_t*)lat32;
    uint2 A0 = *(const uint2*)(lat32 + (r << 4) + (h << 1));
    uint2 A1 = *(const uint2*)(lat32 + 2048 + (r << 4) + (h << 1));
    uint2 D0 = *(const uint2*)(lat32 + (((r + 1) & 127) << 4) + (h << 1));
    uint2 D1 = *(const uint2*)(lat32 + 2048 + (((r + 1) & 127) << 4) + (h << 1));
    uint32_t e2 = latb[(r << 6) + (((h << 3) + 8) & 63)];   // P0 row r
    uint32_t xs0 = (A0.x >> 8) | (A0.y << 24);
    uint32_t xs1 = (A0.y >> 8) | (e2 << 24);
    uint32_t tx = (A0.x ^ D0.x) + (A1.x ^ D1.x) + (A0.x ^ A1.x) + (A1.x ^ xs0);
    uint32_t ty = (A0.y ^ D0.y) + (A1.y ^ D1.y) + (A0.y ^ A1.y) + (A1.y ^ xs1);
    int psum = (int)((tx * 0x01010101u) >> 24) + (int)((ty * 0x01010101u) >> 24);
#pragma unroll
    for (int o = 32; o > 0; o >>= 1) psum += __shfl_down(psum, o, 64);
    if ((t & 63) == 0) wred[t >> 6] = psum;
    __syncthreads();
    if (t == 0) {
      int tot = 0;
#pragma unroll
      for (int i = 0; i < 16; ++i) tot += wred[i];
      Ecur[(bp << 4) | c] = (float)(2 * tot - 32768);
    }
  }

  if (store_back) {
    ((uint4*)sg)[(w << 10) + t] = ((const uint4*)lat32)[t];
  }
}

// ---------------- host ----------------
extern "C" void kernel_launch(void* const* d_in, const int* in_sizes, int n_in,
                              void* d_out, int out_size, void* d_ws, size_t ws_size,
                              hipStream_t stream) {
  const float* spins_in = (const float*)d_in[0];
  const float* T        = (const float*)d_in[1];
  uint32_t* s   = (uint32_t*)d_ws;                          // 4 MB lattice
  float*  Ea    = (float*)((char*)d_ws + (4u << 20));       // 1 KB
  float*  Eb    = (float*)((char*)d_ws + (4u << 20) + 1024);
  int*  slotmap = (int*)((char*)d_ws + (4u << 20) + 2048);  // 1 KB
  float*  out = (float*)d_out;

  // chunks split at PT events (after sweeps 0,5,10,15); samples after 14,19
  const int starts[5]  = {0, 1, 6, 11, 16};
  const int counts[5]  = {1, 5, 5, 5, 4};
  const int samploc[5] = {-1, -1, -1, 3, 3};
  const int sampidx[5] = {0, 0, 0, 0, 1};
  const int writeE[5]  = {1, 1, 1, 1, 0};
  const int storeB[5]  = {1, 1, 1, 1, 0};

  for (int ch = 0; ch < 5; ++ch) {
    float* Ecur  = (ch & 1) ? Eb : Ea;
    float* Eprev = (ch & 1) ? Ea : Eb;
    k_chunk<<<256, 1024, 0, stream>>>((const float4*)spins_in, s, T, slotmap,
                                      Eprev, Ecur, out,
                                      ch, starts[ch], counts[ch],
                                      samploc[ch], sampidx[ch],
                                      writeE[ch], storeB[ch]);
  }
}